// Round 9
// baseline (133.188 us; speedup 1.0000x reference)
//
#include <hip/hip_runtime.h>
#include <hip/hip_fp16.h>
#include <math.h>

#define N_NODES 50000
#define N_EDGES 800000
#define CAP 64   // max out-degree bucket capacity (realized max ~40, Poisson(16))

typedef __attribute__((ext_vector_type(8)))  short s16x8;   // 8 bf16 (4 VGPR)
typedef __attribute__((ext_vector_type(16))) float f32x16;  // MFMA acc
typedef unsigned int u32;
typedef unsigned short u16;

union U16B { uint4 u; s16x8 s; };

// f32 -> bf16 bits, round-to-nearest-even
__device__ __forceinline__ u32 bfr(float f) {
    u32 u = __float_as_uint(f);
    return (u + 0x7FFFu + ((u >> 16) & 1u)) >> 16;
}
__device__ __forceinline__ u32 pkbf(float a, float b) { return bfr(a) | (bfr(b) << 16); }
__device__ __forceinline__ float bf2f(u32 b) { return __uint_as_float(b << 16); }
// dot of a bf16x2 pair against another
__device__ __forceinline__ float dotpair(u32 a, u32 b) {
    return bf2f(a & 0xFFFFu) * bf2f(b & 0xFFFFu) + bf2f(a >> 16) * bf2f(b >> 16);
}

// Build an MFMA input frag (lane-dim = D-col, k = 8*(lane>>5)+e) from 8 f32
// D-regs of a 32x32x16 accumulator (rows (r&3)+8*(r>>2)+4*hh), via bf16 pack
// + half-wave exchange. d8 must be compile-time indexed by caller.
__device__ __forceinline__ uint4 buildfrag(const float* d8, int hh) {
    u32 P = pkbf(d8[0], d8[1]), Q = pkbf(d8[2], d8[3]);
    u32 R = pkbf(d8[4], d8[5]), S = pkbf(d8[6], d8[7]);
    u32 sP = (u32)__shfl_xor((int)P, 32);
    u32 sQ = (u32)__shfl_xor((int)Q, 32);
    u32 sR = (u32)__shfl_xor((int)R, 32);
    u32 sS = (u32)__shfl_xor((int)S, 32);
    uint4 f;
    f.x = hh ? sR : P;  f.y = hh ? sS : Q;
    f.z = hh ? R : sP;  f.w = hh ? S : sQ;
    return f;
}
#define BUILDF(OUT, ACC, Q, HH) do { \
    float _td[8]; \
    _Pragma("unroll") for (int _z = 0; _z < 8; ++_z) _td[_z] = (ACC)[(Q)*8 + _z]; \
    (OUT) = buildfrag(_td, HH); } while (0)
#define BUILDR(OUT, ACC, Q, HH) do { \
    float _td[8]; \
    _Pragma("unroll") for (int _z = 0; _z < 8; ++_z) _td[_z] = fmaxf((ACC)[(Q)*8 + _z], 0.f); \
    (OUT) = buildfrag(_td, HH); } while (0)

// ---------------------------------------------------------------------------
// prep: weights -> bf16, transposed [col][k] rows (256B), granule-XOR swizzled
// ---------------------------------------------------------------------------
__global__ __launch_bounds__(256) void k_prep(
    const float* __restrict__ enc_w, const float* __restrict__ msg_w,
    const float* __restrict__ sig_w, const float* __restrict__ agg_w,
    const float* __restrict__ dec_w,
    uint4* __restrict__ WtE, uint4* __restrict__ WtM, uint4* __restrict__ WtD,
    uint4* __restrict__ WtA0, uint4* __restrict__ WtA1, uint4* __restrict__ WtS)
{
    int gid = blockIdx.x * 256 + threadIdx.x;
    if (gid < 10240) {
        int m = gid >> 11, r = gid & 2047;
        int col = r >> 4, s = r & 15;
        const float* W; uint4* D; int kb = 0;
        if      (m == 0) { W = enc_w; D = WtE; }
        else if (m == 1) { W = msg_w; D = WtM; }
        else if (m == 2) { W = dec_w; D = WtD; }
        else if (m == 3) { W = agg_w; D = WtA0; }
        else             { W = agg_w; D = WtA1; kb = 128; }
        float v[8];
        #pragma unroll
        for (int j = 0; j < 8; ++j) v[j] = W[(size_t)(kb + s * 8 + j) * 128 + col];
        uint4 w;
        w.x = pkbf(v[0], v[1]); w.y = pkbf(v[2], v[3]);
        w.z = pkbf(v[4], v[5]); w.w = pkbf(v[6], v[7]);
        D[col * 16 + (s ^ (col & 7))] = w;
    } else if (gid < 10752) {
        int r = gid - 10240;
        int row = r >> 4, s = r & 15;
        float v[8];
        #pragma unroll
        for (int j = 0; j < 8; ++j)
            v[j] = (row < 16) ? sig_w[(size_t)(s * 8 + j) * 16 + row] : 0.0f;
        uint4 w;
        w.x = pkbf(v[0], v[1]); w.y = pkbf(v[2], v[3]);
        w.z = pkbf(v[4], v[5]); w.w = pkbf(v[6], v[7]);
        WtS[row * 16 + (s ^ (row & 7))] = w;
    }
}

// ---------------------------------------------------------------------------
// encode (MFMA): h = x@enc_w+b ; msg = relu(h@msg_w+b) ; sig = l2n(h@sig_w+b)
// Block = 128 nodes, 4 waves x 32 nodes. All GEMMs computed transposed
// (D = W^T x^T) so lane-dim = node; h^T fragments stay in registers.
// ---------------------------------------------------------------------------
__global__ __launch_bounds__(256) void k_encode_m(
    const float* __restrict__ x,
    const uint4* __restrict__ WtE, const uint4* __restrict__ WtM,
    const uint4* __restrict__ WtS,
    const float* __restrict__ enc_b, const float* __restrict__ sig_b,
    const float* __restrict__ msg_b,
    uint4* __restrict__ h_g, u32* __restrict__ sig_bf, uint4* __restrict__ msg_g)
{
    __shared__ uint4 LB[2048];   // x tile bf16 [128 nodes][16 granules]
    __shared__ uint4 LW[2048];   // weight tile [128 cols][16 granules]
    __shared__ float LS[2176];   // sigWt (8KB) then sig funnel (8.7KB)

    const int t = threadIdx.x;
    const int node0 = blockIdx.x * 128;
    int nrem = N_NODES - node0; if (nrem > 128) nrem = 128;
    const int lane = t & 63, wid = t >> 6;
    const int l31 = lane & 31, hh = lane >> 5;
    const int nloc = wid * 32 + l31;
    const int sw7 = l31 & 7;

    // stage x (f32->bf16, swizzled) + enc weights
    #pragma unroll
    for (int it = 0; it < 8; ++it) {
        int idx = it * 256 + t;
        int nd = idx >> 4, s = idx & 15;
        float4 v0 = make_float4(0, 0, 0, 0), v1 = v0;
        if (nd < nrem) {
            const float4* px = (const float4*)(x + (size_t)(node0 + nd) * 128 + s * 8);
            v0 = px[0]; v1 = px[1];
        }
        uint4 w;
        w.x = pkbf(v0.x, v0.y); w.y = pkbf(v0.z, v0.w);
        w.z = pkbf(v1.x, v1.y); w.w = pkbf(v1.z, v1.w);
        LB[nd * 16 + (s ^ (nd & 7))] = w;
        LW[idx] = WtE[idx];
    }
    __syncthreads();

    const char* lb = (const char*)LB;
    const char* lw = (const char*)LW;

    // GEMM1: h^T = encW^T x^T  (D rows = h-cols, cols = nodes)
    f32x16 a0 = {}, a1 = {}, a2 = {}, a3 = {};
    #pragma unroll
    for (int r = 0; r < 16; ++r) {
        int rr = (r & 3) + 8 * (r >> 2) + 4 * hh;
        a0[r] = enc_b[rr];      a1[r] = enc_b[32 + rr];
        a2[r] = enc_b[64 + rr]; a3[r] = enc_b[96 + rr];
    }
    #pragma unroll
    for (int ks = 0; ks < 8; ++ks) {
        int so = ((ks * 2 + hh) ^ sw7) << 4;
        s16x8 bf = *(const s16x8*)(lb + nloc * 256 + so);
        s16x8 w0 = *(const s16x8*)(lw + l31 * 256 + so);
        s16x8 w1 = *(const s16x8*)(lw + 8192 + l31 * 256 + so);
        s16x8 w2 = *(const s16x8*)(lw + 16384 + l31 * 256 + so);
        s16x8 w3 = *(const s16x8*)(lw + 24576 + l31 * 256 + so);
        a0 = __builtin_amdgcn_mfma_f32_32x32x16_bf16(w0, bf, a0, 0, 0, 0);
        a1 = __builtin_amdgcn_mfma_f32_32x32x16_bf16(w1, bf, a1, 0, 0, 0);
        a2 = __builtin_amdgcn_mfma_f32_32x32x16_bf16(w2, bf, a2, 0, 0, 0);
        a3 = __builtin_amdgcn_mfma_f32_32x32x16_bf16(w3, bf, a3, 0, 0, 0);
    }

    // h^T -> in-register bf16 fragments (k = h-col)
    uint4 hf[8];
    BUILDF(hf[0], a0, 0, hh); BUILDF(hf[1], a0, 1, hh);
    BUILDF(hf[2], a1, 0, hh); BUILDF(hf[3], a1, 1, hh);
    BUILDF(hf[4], a2, 0, hh); BUILDF(hf[5], a2, 1, hh);
    BUILDF(hf[6], a3, 0, hh); BUILDF(hf[7], a3, 1, hh);

    // h rows -> global (pre-swizzled bf16 rows)
    if (nloc < nrem) {
        const size_t rb = (size_t)(node0 + nloc) * 16;
        #pragma unroll
        for (int f = 0; f < 8; ++f) {
            int g = 2 * f + hh;
            h_g[rb + (g ^ sw7)] = hf[f];
        }
    }

    __syncthreads();   // done reading WtE
    #pragma unroll
    for (int it = 0; it < 8; ++it) LW[it * 256 + t] = WtM[it * 256 + t];
    {   // sigWt (8KB) into LS
        uint4* LSu = (uint4*)LS;
        LSu[t] = WtS[t]; LSu[256 + t] = WtS[256 + t];
    }
    __syncthreads();

    // GEMM2: msg^T = msgW^T h^T  (B-operand = in-reg h frags)
    f32x16 m0 = {}, m1 = {}, m2 = {}, m3 = {};
    #pragma unroll
    for (int r = 0; r < 16; ++r) {
        int rr = (r & 3) + 8 * (r >> 2) + 4 * hh;
        m0[r] = msg_b[rr];      m1[r] = msg_b[32 + rr];
        m2[r] = msg_b[64 + rr]; m3[r] = msg_b[96 + rr];
    }
    #pragma unroll
    for (int ks = 0; ks < 8; ++ks) {
        int so = ((ks * 2 + hh) ^ sw7) << 4;
        U16B hb; hb.u = hf[ks];
        s16x8 w0 = *(const s16x8*)(lw + l31 * 256 + so);
        s16x8 w1 = *(const s16x8*)(lw + 8192 + l31 * 256 + so);
        s16x8 w2 = *(const s16x8*)(lw + 16384 + l31 * 256 + so);
        s16x8 w3 = *(const s16x8*)(lw + 24576 + l31 * 256 + so);
        m0 = __builtin_amdgcn_mfma_f32_32x32x16_bf16(w0, hb.s, m0, 0, 0, 0);
        m1 = __builtin_amdgcn_mfma_f32_32x32x16_bf16(w1, hb.s, m1, 0, 0, 0);
        m2 = __builtin_amdgcn_mfma_f32_32x32x16_bf16(w2, hb.s, m2, 0, 0, 0);
        m3 = __builtin_amdgcn_mfma_f32_32x32x16_bf16(w3, hb.s, m3, 0, 0, 0);
    }
    {   // relu + store msg rows
        uint4 mf[8];
        BUILDR(mf[0], m0, 0, hh); BUILDR(mf[1], m0, 1, hh);
        BUILDR(mf[2], m1, 0, hh); BUILDR(mf[3], m1, 1, hh);
        BUILDR(mf[4], m2, 0, hh); BUILDR(mf[5], m2, 1, hh);
        BUILDR(mf[6], m3, 0, hh); BUILDR(mf[7], m3, 1, hh);
        if (nloc < nrem) {
            const size_t rb = (size_t)(node0 + nloc) * 16;
            #pragma unroll
            for (int f = 0; f < 8; ++f) {
                int g = 2 * f + hh;
                msg_g[rb + (g ^ sw7)] = mf[f];
            }
        }
    }

    // GEMM3: sig^T = sigW^T h^T  (rows 16..31 of sigWt are zero)
    f32x16 sg = {};
    #pragma unroll
    for (int r = 0; r < 8; ++r) {
        int rr = (r & 3) + 8 * (r >> 2) + 4 * hh;   // < 16
        sg[r] = sig_b[rr];
    }
    const char* lsw = (const char*)LS;
    #pragma unroll
    for (int ks = 0; ks < 8; ++ks) {
        int so = ((ks * 2 + hh) ^ sw7) << 4;
        s16x8 aw = *(const s16x8*)(lsw + l31 * 256 + so);
        U16B hb; hb.u = hf[ks];
        sg = __builtin_amdgcn_mfma_f32_32x32x16_bf16(aw, hb.s, sg, 0, 0, 0);
    }
    float ss = 0.f;
    #pragma unroll
    for (int r = 0; r < 8; ++r) ss += sg[r] * sg[r];
    ss += __shfl_xor(ss, 32);
    float inv = 1.0f / fmaxf(sqrtf(ss), 1e-12f);
    __syncthreads();   // all sigWt reads done before funnel overwrite
    #pragma unroll
    for (int r = 0; r < 8; ++r) {
        int sc = (r & 3) + 8 * (r >> 2) + 4 * hh;
        LS[nloc * 17 + sc] = sg[r] * inv;
    }
    __syncthreads();
    // sig rows -> global as bf16 pairs (8 u32 per node)
    #pragma unroll
    for (int it = 0; it < 4; ++it) {
        int idx = it * 256 + t;           // 1024 = 128 nodes x 8 u32
        int nd = idx >> 3, c2 = idx & 7;
        if (nd < nrem)
            sig_bf[(size_t)(node0 + nd) * 8 + c2] =
                pkbf(LS[nd * 17 + 2 * c2], LS[nd * 17 + 2 * c2 + 1]);
    }
}

// ---------------------------------------------------------------------------
// decode (MFMA): out = relu([h|comm]@agg_w+b) @ dec_w + b
// Block = 64 nodes, 4 waves: wave = (node half) x (64 col half).
// ---------------------------------------------------------------------------
__global__ __launch_bounds__(256) void k_decode_m(
    const uint4* __restrict__ h_g, const uint4* __restrict__ comm,
    const uint4* __restrict__ WtA0, const uint4* __restrict__ WtA1,
    const uint4* __restrict__ WtD,
    const float* __restrict__ agg_b, const float* __restrict__ dec_b,
    float* __restrict__ out)
{
    __shared__ uint4 LB[2048];   // Bcat [64][32 granules]; later Lcomb [64][16]
    __shared__ uint4 LW[2048];

    const int t = threadIdx.x;
    const int node0 = blockIdx.x * 64;
    int nrem = N_NODES - node0; if (nrem > 64) nrem = 64;
    const int lane = t & 63, wid = t >> 6;
    const int l31 = lane & 31, hh = lane >> 5;
    const int ng = wid & 1, cp = wid >> 1;
    const int nloc = ng * 32 + l31;
    const int sw7 = l31 & 7;

    // stage Bcat = [h | comm] bf16 (both pre-swizzled: linear copy)
    #pragma unroll
    for (int it = 0; it < 8; ++it) {
        int idx = it * 256 + t;
        int nd = idx >> 5, g = idx & 31;
        uint4 v = make_uint4(0, 0, 0, 0);
        if (nd < nrem)
            v = (g < 16) ? h_g[(size_t)(node0 + nd) * 16 + g]
                         : comm[(size_t)(node0 + nd) * 16 + (g - 16)];
        LB[nd * 32 + g] = v;
        LW[idx] = WtA0[idx];
    }
    __syncthreads();

    const char* lb = (const char*)LB;
    const char* lw = (const char*)LW;

    // GEMM-A: combined^T = aggW^T [h|comm]^T  (K = 256, staged in halves)
    f32x16 c0 = {}, c1 = {};
    #pragma unroll
    for (int r = 0; r < 16; ++r) {
        int rr = (r & 3) + 8 * (r >> 2) + 4 * hh;
        c0[r] = agg_b[cp * 64 + rr];
        c1[r] = agg_b[cp * 64 + 32 + rr];
    }
    #pragma unroll
    for (int ks = 0; ks < 8; ++ks) {
        int so = ((ks * 2 + hh) ^ sw7) << 4;
        s16x8 bf = *(const s16x8*)(lb + nloc * 512 + so);
        s16x8 w0 = *(const s16x8*)(lw + (cp * 64 + l31) * 256 + so);
        s16x8 w1 = *(const s16x8*)(lw + (cp * 64 + 32 + l31) * 256 + so);
        c0 = __builtin_amdgcn_mfma_f32_32x32x16_bf16(w0, bf, c0, 0, 0, 0);
        c1 = __builtin_amdgcn_mfma_f32_32x32x16_bf16(w1, bf, c1, 0, 0, 0);
    }
    __syncthreads();
    #pragma unroll
    for (int it = 0; it < 8; ++it) LW[it * 256 + t] = WtA1[it * 256 + t];
    __syncthreads();
    #pragma unroll
    for (int ks = 8; ks < 16; ++ks) {
        int so = ((ks * 2 + hh) ^ sw7) << 4;            // bit4 kept: comm half
        int so2 = (((ks - 8) * 2 + hh) ^ sw7) << 4;
        s16x8 bf = *(const s16x8*)(lb + nloc * 512 + so);
        s16x8 w0 = *(const s16x8*)(lw + (cp * 64 + l31) * 256 + so2);
        s16x8 w1 = *(const s16x8*)(lw + (cp * 64 + 32 + l31) * 256 + so2);
        c0 = __builtin_amdgcn_mfma_f32_32x32x16_bf16(w0, bf, c0, 0, 0, 0);
        c1 = __builtin_amdgcn_mfma_f32_32x32x16_bf16(w1, bf, c1, 0, 0, 0);
    }
    __syncthreads();   // all Bcat / WtA1 reads done

    // relu + build combined fragments; exchange across waves via LB (Lcomb)
    {
        uint4 cf[4];
        BUILDR(cf[0], c0, 0, hh); BUILDR(cf[1], c0, 1, hh);
        BUILDR(cf[2], c1, 0, hh); BUILDR(cf[3], c1, 1, hh);
        #pragma unroll
        for (int f = 0; f < 4; ++f) {
            int g = (cp * 4 + f) * 2 + hh;
            LB[nloc * 16 + (g ^ sw7)] = cf[f];
        }
    }
    #pragma unroll
    for (int it = 0; it < 8; ++it) LW[it * 256 + t] = WtD[it * 256 + t];
    __syncthreads();

    // GEMM-B: out = combined @ dec_w  (A = in-LDS combined frags, lane = outcol)
    f32x16 o0 = {}, o1 = {};
    {
        float b0 = dec_b[cp * 64 + l31], b1 = dec_b[cp * 64 + 32 + l31];
        #pragma unroll
        for (int r = 0; r < 16; ++r) { o0[r] = b0; o1[r] = b1; }
    }
    #pragma unroll
    for (int ks = 0; ks < 8; ++ks) {
        int so = ((ks * 2 + hh) ^ sw7) << 4;
        s16x8 af = *(const s16x8*)(lb + nloc * 256 + so);
        s16x8 w0 = *(const s16x8*)(lw + (cp * 64 + l31) * 256 + so);
        s16x8 w1 = *(const s16x8*)(lw + (cp * 64 + 32 + l31) * 256 + so);
        o0 = __builtin_amdgcn_mfma_f32_32x32x16_bf16(af, w0, o0, 0, 0, 0);
        o1 = __builtin_amdgcn_mfma_f32_32x32x16_bf16(af, w1, o1, 0, 0, 0);
    }
    #pragma unroll
    for (int r = 0; r < 16; ++r) {
        int nd = ng * 32 + (r & 3) + 8 * (r >> 2) + 4 * hh;
        if (nd < nrem) {
            float* row = out + (size_t)(node0 + nd) * 128 + cp * 64;
            row[l31]      = o0[r];
            row[32 + l31] = o1[r];
        }
    }
}

// ---------------------------------------------------------------------------
// scatter into per-src buckets, 4 edges/thread, 4-B entries (d:16 | e:fp16)
//   e = exp(dot(sig[src], sig[dst]))   (|dot|<=1: segment_max elision exact)
// ---------------------------------------------------------------------------
__global__ __launch_bounds__(256) void k_scatter_b(
    const int* __restrict__ src, const int* __restrict__ dst,
    const u32* __restrict__ sig_bf,
    int* __restrict__ counts, u32* __restrict__ bucket)
{
    int e0 = blockIdx.x * 1024 + threadIdx.x;
    #pragma unroll
    for (int r = 0; r < 4; ++r) {
        int e = e0 + r * 256;
        if (e < N_EDGES) {
            int s = src[e], d = dst[e];
            const uint4* ps = (const uint4*)(sig_bf + (size_t)s * 8);
            const uint4* pd = (const uint4*)(sig_bf + (size_t)d * 8);
            uint4 sa = ps[0], sb = ps[1];
            uint4 da = pd[0], db = pd[1];
            float dot = dotpair(sa.x, da.x) + dotpair(sa.y, da.y)
                      + dotpair(sa.z, da.z) + dotpair(sa.w, da.w)
                      + dotpair(sb.x, db.x) + dotpair(sb.y, db.y)
                      + dotpair(sb.z, db.z) + dotpair(sb.w, db.w);
            float ev = __expf(dot);
            u32 h = (u32)__half_as_ushort(__float2half(ev));
            int pos = atomicAdd(&counts[s], 1);
            bucket[(size_t)s * CAP + pos] = (u32)d | (h << 16);
        }
    }
}

// one wave per node, lane = 2 dims (bf16 pairs); msg/comm rows pre-swizzled
__global__ __launch_bounds__(256) void k_aggr_b(
    const int* __restrict__ counts, const u32* __restrict__ bucket,
    const char* __restrict__ msg_g, char* __restrict__ comm)
{
    const int wave = threadIdx.x >> 6;
    const int lane = threadIdx.x & 63;
    int node = blockIdx.x * 4 + wave;
    if (node >= N_NODES) return;
    const int cnt = counts[node];
    const u32* bk = bucket + (size_t)node * CAP;
    const int lo4 = 4 * lane;
    float ax = 0.f, ay = 0.f, den = 0.f;
    int k = 0;
    for (; k + 4 <= cnt; k += 4) {
        u32 b0 = bk[k], b1 = bk[k + 1], b2 = bk[k + 2], b3 = bk[k + 3];
        int d0 = b0 & 0xFFFF, d1 = b1 & 0xFFFF, d2 = b2 & 0xFFFF, d3 = b3 & 0xFFFF;
        float e0 = __half2float(__ushort_as_half((u16)(b0 >> 16)));
        float e1 = __half2float(__ushort_as_half((u16)(b1 >> 16)));
        float e2 = __half2float(__ushort_as_half((u16)(b2 >> 16)));
        float e3 = __half2float(__ushort_as_half((u16)(b3 >> 16)));
        u32 m0 = *(const u32*)(msg_g + (size_t)d0 * 256 + (lo4 ^ ((d0 & 7) << 4)));
        u32 m1 = *(const u32*)(msg_g + (size_t)d1 * 256 + (lo4 ^ ((d1 & 7) << 4)));
        u32 m2 = *(const u32*)(msg_g + (size_t)d2 * 256 + (lo4 ^ ((d2 & 7) << 4)));
        u32 m3 = *(const u32*)(msg_g + (size_t)d3 * 256 + (lo4 ^ ((d3 & 7) << 4)));
        ax += e0 * bf2f(m0 & 0xFFFF) + e1 * bf2f(m1 & 0xFFFF)
            + e2 * bf2f(m2 & 0xFFFF) + e3 * bf2f(m3 & 0xFFFF);
        ay += e0 * bf2f(m0 >> 16) + e1 * bf2f(m1 >> 16)
            + e2 * bf2f(m2 >> 16) + e3 * bf2f(m3 >> 16);
        den += e0 + e1 + e2 + e3;
    }
    for (; k < cnt; ++k) {
        u32 b = bk[k];
        int dn = b & 0xFFFF;
        float ev = __half2float(__ushort_as_half((u16)(b >> 16)));
        u32 m = *(const u32*)(msg_g + (size_t)dn * 256 + (lo4 ^ ((dn & 7) << 4)));
        ax += ev * bf2f(m & 0xFFFF);
        ay += ev * bf2f(m >> 16);
        den += ev;
    }
    float inv = (den > 0.f) ? (1.0f / den) : 0.f;
    *(u32*)(comm + (size_t)node * 256 + (lo4 ^ ((node & 7) << 4))) = pkbf(ax * inv, ay * inv);
}

// ---------------------------------------------------------------------------
extern "C" void kernel_launch(void* const* d_in, const int* in_sizes, int n_in,
                              void* d_out, int out_size, void* d_ws, size_t ws_size,
                              hipStream_t stream)
{
    const float* x     = (const float*)d_in[0];
    const int*   ei    = (const int*)  d_in[1];
    const float* enc_w = (const float*)d_in[2];
    const float* enc_b = (const float*)d_in[3];
    const float* sig_w = (const float*)d_in[4];
    const float* sig_b = (const float*)d_in[5];
    const float* msg_w = (const float*)d_in[6];
    const float* msg_b = (const float*)d_in[7];
    const float* agg_w = (const float*)d_in[8];
    const float* agg_b = (const float*)d_in[9];
    const float* dec_w = (const float*)d_in[10];
    const float* dec_b = (const float*)d_in[11];
    float* out = (float*)d_out;

    const int* src = ei;            // edge_index[0]
    const int* dst = ei + N_EDGES;  // edge_index[1]

    // workspace layout (bytes), ~53 MB
    char* p = (char*)d_ws;
    uint4* h_g   = (uint4*)p;  p += (size_t)N_NODES * 256;  // bf16 rows, swizzled
    uint4* msg_g = (uint4*)p;  p += (size_t)N_NODES * 256;
    uint4* comm  = (uint4*)p;  p += (size_t)N_NODES * 256;
    u32*   sig_bf = (u32*)p;   p += (size_t)N_NODES * 32;   // bf16 sig rows
    u32*   bucket = (u32*)p;   p += (size_t)N_NODES * CAP * 4;
    int*   counts = (int*)p;   p += (size_t)N_NODES * 4;
    uint4* WtE  = (uint4*)p; p += 32768;
    uint4* WtM  = (uint4*)p; p += 32768;
    uint4* WtD  = (uint4*)p; p += 32768;
    uint4* WtA0 = (uint4*)p; p += 32768;
    uint4* WtA1 = (uint4*)p; p += 32768;
    uint4* WtS  = (uint4*)p; p += 8192;

    hipMemsetAsync(counts, 0, (size_t)N_NODES * sizeof(int), stream);

    k_prep<<<42, 256, 0, stream>>>(enc_w, msg_w, sig_w, agg_w, dec_w,
                                   WtE, WtM, WtD, WtA0, WtA1, WtS);
    k_encode_m<<<(N_NODES + 127) / 128, 256, 0, stream>>>(
        x, WtE, WtM, WtS, enc_b, sig_b, msg_b, h_g, sig_bf, msg_g);
    k_scatter_b<<<(N_EDGES + 1023) / 1024, 256, 0, stream>>>(
        src, dst, sig_bf, counts, bucket);
    k_aggr_b<<<(N_NODES + 3) / 4, 256, 0, stream>>>(
        counts, bucket, (const char*)msg_g, (char*)comm);
    k_decode_m<<<(N_NODES + 63) / 64, 256, 0, stream>>>(
        h_g, comm, WtA0, WtA1, WtD, agg_b, dec_b, out);
}